// Round 2
// baseline (331.539 us; speedup 1.0000x reference)
//
#include <hip/hip_runtime.h>

#define NGROUPS 16          // G
#define TPG     16          // threads per group = (D/G)/8 = 128/8
#define CHUNK   32          // timesteps per chunk
#define EPS_F   1e-5f
#define VFLOOR  1e-6f

__device__ __forceinline__ float sum8(const float4& a, const float4& b) {
    return ((a.x + a.y) + (a.z + a.w)) + ((b.x + b.y) + (b.z + b.w));
}

// ---------------- Kernel A: per-chunk local Welford aggregates ----------------
// grid = B*NC blocks, block = D/8 = 256 threads. Block handles one (b, chunk)
// for all 16 groups. Thread tid covers elements [tid*8, tid*8+8) of each row;
// group g = tid/16 (all 8 elements of a thread lie in one group since gs=128).
__global__ void __launch_bounds__(256)
ts_chunk_agg(const float* __restrict__ x, const int* __restrict__ mask,
             float* __restrict__ loc_n, float* __restrict__ loc_mean,
             float* __restrict__ loc_m2,
             int B, int L, int D, int NC, float inv_gs)
{
    const int b   = blockIdx.x / NC;
    const int c   = blockIdx.x % NC;
    const int tid = threadIdx.x;
    const int g   = tid / TPG;
    const int t0  = c * CHUNK;
    const int t1  = min(t0 + CHUNK, L);

    const float* xb = x + (size_t)b * L * D + tid * 8;
    const int* mb = mask + (size_t)b * L;

    float n = 0.f, mean = 0.f, m2 = 0.f;
    #pragma unroll 4
    for (int t = t0; t < t1; ++t) {
        const float4* p = (const float4*)(xb + (size_t)t * D);
        float4 v0 = p[0], v1 = p[1];
        float s = sum8(v0, v1);
        // reduce across the 16 lanes of this group (within a wave)
        s += __shfl_xor(s, 1, 64);
        s += __shfl_xor(s, 2, 64);
        s += __shfl_xor(s, 4, 64);
        s += __shfl_xor(s, 8, 64);
        float gm = s * inv_gs;
        if (mb[t]) {                     // uniform branch (mask is per-(b,t))
            n += 1.f;
            float d = gm - mean;
            mean += __fdividef(d, n);
            m2 = fmaf(d, gm - mean, m2);
        }
    }
    if ((tid & (TPG - 1)) == 0) {
        int idx = c * (B * NGROUPS) + b * NGROUPS + g;   // [c][b][g] coalesced layout
        loc_n[idx] = n; loc_mean[idx] = mean; loc_m2[idx] = m2;
    }
}

// ---------------- Kernel B: serial Chan-merge scan over chunks ----------------
// one block, B*G threads; thread = one (b,g) chain, NC serial merges each.
__global__ void ts_scan(const int* __restrict__ prev_count,
                        const float* __restrict__ prev_mean,
                        const float* __restrict__ prev_var,
                        const float* __restrict__ loc_n,
                        const float* __restrict__ loc_mean,
                        const float* __restrict__ loc_m2,
                        float* __restrict__ pref_n, float* __restrict__ pref_mean,
                        float* __restrict__ pref_m2,
                        float* __restrict__ out_count,
                        int B, int NC)
{
    const int chain = threadIdx.x;           // = b*G + g
    const int BG = B * NGROUPS;
    if (chain >= BG) return;
    const int b = chain / NGROUPS;
    const int g = chain % NGROUPS;

    float n    = (float)prev_count[b];
    float mean = prev_mean[chain];
    float m2   = prev_var[chain] * fmaxf(n, 1.0f);   // prev_m2 per reference

    for (int c = 0; c < NC; ++c) {
        const int idx = c * BG + chain;
        pref_n[idx] = n; pref_mean[idx] = mean; pref_m2[idx] = m2;
        float nb = loc_n[idx];
        if (nb > 0.f) {
            float mb_ = loc_mean[idx];
            float m2b = loc_m2[idx];
            float nn  = n + nb;
            float d   = mb_ - mean;
            float r   = nb / nn;
            mean += d * r;
            m2   += m2b + d * d * (n * r);
            n = nn;
        }
    }
    if (g == 0) out_count[b] = n;   // new_count, stored as fp32 (whole d_out is fp32)
}

// ---------------- Kernel C: replay + normalize ----------------
__global__ void __launch_bounds__(256)
ts_norm(const float* __restrict__ x, const int* __restrict__ mask,
        const float* __restrict__ weight, const float* __restrict__ bias,
        const float* __restrict__ pref_n, const float* __restrict__ pref_mean,
        const float* __restrict__ pref_m2,
        float* __restrict__ y, float* __restrict__ out_mean,
        float* __restrict__ out_var,
        int B, int L, int D, int NC, float inv_gs)
{
    const int b   = blockIdx.x / NC;
    const int c   = blockIdx.x % NC;
    const int tid = threadIdx.x;
    const int g   = tid / TPG;
    const int chain = b * NGROUPS + g;
    const int idx   = c * (B * NGROUPS) + chain;

    float n    = pref_n[idx];
    float mean = pref_mean[idx];
    float m2   = pref_m2[idx];

    // per-thread affine params (loop-invariant)
    const float4* wp = (const float4*)(weight + tid * 8);
    const float4* hp = (const float4*)(bias + tid * 8);
    float4 w0 = wp[0], w1 = wp[1];
    float4 h0 = hp[0], h1 = hp[1];
    w0.x += 1.f; w0.y += 1.f; w0.z += 1.f; w0.w += 1.f;
    w1.x += 1.f; w1.y += 1.f; w1.z += 1.f; w1.w += 1.f;

    const int t0 = c * CHUNK;
    const int t1 = min(t0 + CHUNK, L);
    const float* xb = x + (size_t)b * L * D + tid * 8;
    float*       yb = y + (size_t)b * L * D + tid * 8;
    const int* mb = mask + (size_t)b * L;

    float var = VFLOOR;
    #pragma unroll 2
    for (int t = t0; t < t1; ++t) {
        const float4* p = (const float4*)(xb + (size_t)t * D);
        float4 v0 = p[0], v1 = p[1];
        float s = sum8(v0, v1);
        s += __shfl_xor(s, 1, 64);
        s += __shfl_xor(s, 2, 64);
        s += __shfl_xor(s, 4, 64);
        s += __shfl_xor(s, 8, 64);
        float gm = s * inv_gs;
        if (mb[t]) {
            n += 1.f;
            float d = gm - mean;
            mean += __fdividef(d, n);
            m2 = fmaf(d, gm - mean, m2);
        }
        var = fmaxf(__fdividef(m2, fmaxf(n, 1.f)), VFLOOR);
        float rstd = rsqrtf(var + EPS_F);

        float4 o0, o1;
        o0.x = fmaf((v0.x - mean) * rstd, w0.x, h0.x);
        o0.y = fmaf((v0.y - mean) * rstd, w0.y, h0.y);
        o0.z = fmaf((v0.z - mean) * rstd, w0.z, h0.z);
        o0.w = fmaf((v0.w - mean) * rstd, w0.w, h0.w);
        o1.x = fmaf((v1.x - mean) * rstd, w1.x, h1.x);
        o1.y = fmaf((v1.y - mean) * rstd, w1.y, h1.y);
        o1.z = fmaf((v1.z - mean) * rstd, w1.z, h1.z);
        o1.w = fmaf((v1.w - mean) * rstd, w1.w, h1.w);
        float4* q = (float4*)(yb + (size_t)t * D);
        q[0] = o0; q[1] = o1;
    }

    // final-state outputs from the last chunk
    if (c == NC - 1 && (tid & (TPG - 1)) == 0) {
        out_mean[chain] = mean;
        out_var[chain]  = var;
    }
}

extern "C" void kernel_launch(void* const* d_in, const int* in_sizes, int n_in,
                              void* d_out, int out_size, void* d_ws, size_t ws_size,
                              hipStream_t stream) {
    const float* x          = (const float*)d_in[0];
    const int*   prev_count = (const int*)d_in[1];
    const float* prev_mean  = (const float*)d_in[2];
    const float* prev_var   = (const float*)d_in[3];
    const int*   mask       = (const int*)d_in[4];     // bool stored as int32
    const float* weight     = (const float*)d_in[5];
    const float* bias       = (const float*)d_in[6];

    const int B  = in_sizes[1];              // prev_count has B elements
    const int D  = in_sizes[5];              // weight has D elements
    const int L  = in_sizes[4] / B;          // mask has B*L elements
    const int NC = (L + CHUNK - 1) / CHUNK;
    const int BG = B * NGROUPS;
    const float inv_gs = (float)NGROUPS / (float)D;   // 1/gs

    float* out = (float*)d_out;
    const size_t yN = (size_t)B * L * D;
    float* out_y     = out;
    float* out_count = out + yN;
    float* out_mean  = out + yN + B;
    float* out_var   = out + yN + B + BG;

    float* ws = (float*)d_ws;
    const size_t stride = (size_t)NC * BG;
    float* loc_n     = ws;
    float* loc_mean  = loc_n + stride;
    float* loc_m2    = loc_mean + stride;
    float* pref_n    = loc_m2 + stride;
    float* pref_mean = pref_n + stride;
    float* pref_m2   = pref_mean + stride;

    dim3 blk(D / 8);   // 256 threads

    ts_chunk_agg<<<B * NC, blk, 0, stream>>>(x, mask, loc_n, loc_mean, loc_m2,
                                             B, L, D, NC, inv_gs);
    ts_scan<<<1, BG, 0, stream>>>(prev_count, prev_mean, prev_var,
                                  loc_n, loc_mean, loc_m2,
                                  pref_n, pref_mean, pref_m2, out_count, B, NC);
    ts_norm<<<B * NC, blk, 0, stream>>>(x, mask, weight, bias,
                                        pref_n, pref_mean, pref_m2,
                                        out_y, out_mean, out_var,
                                        B, L, D, NC, inv_gs);
}

// Round 3
// 322.423 us; speedup vs baseline: 1.0283x; 1.0283x over previous
//
#include <hip/hip_runtime.h>

#define NGROUPS 16          // G
#define TPG     16          // threads per group = (D/G)/8 = 128/8
#define CHUNK   32          // timesteps per chunk
#define EPS_F   1e-5f
#define VFLOOR  1e-6f

__device__ __forceinline__ float sum8(const float4& a, const float4& b) {
    return ((a.x + a.y) + (a.z + a.w)) + ((b.x + b.y) + (b.z + b.w));
}

// ---------------- K1: group means + per-chunk Welford aggregates ----------------
// grid = B*NC, block = D/8 = 256. Reads x once (the only full read of x besides K4).
// gm layout: [b][c][g][j]  (j = t within chunk)  -> contiguous per (chain,chunk) for K3.
// loc layout: [k][c][b*G+g], k=0(n),1(mean),2(m2) -> coalesced for K2 preload.
__global__ void __launch_bounds__(256)
ts_gm_agg(const float* __restrict__ x, const int* __restrict__ mask,
          float* __restrict__ gm_buf, float* __restrict__ loc,
          int B, int L, int D, int NC, float inv_gs)
{
    const int b   = blockIdx.x / NC;
    const int c   = blockIdx.x % NC;
    const int tid = threadIdx.x;
    const int g   = tid / TPG;
    const bool leader = (tid & (TPG - 1)) == 0;
    const int t0  = c * CHUNK;
    const int t1  = min(t0 + CHUNK, L);

    const float* xb = x + (size_t)b * L * D + tid * 8;
    const int*   mb = mask + (size_t)b * L;
    float* gmo = gm_buf + (((size_t)b * NC + c) * NGROUPS + g) * CHUNK;

    float n = 0.f, mean = 0.f, m2 = 0.f;
    #pragma unroll 4
    for (int t = t0; t < t1; ++t) {
        const float4* p = (const float4*)(xb + (size_t)t * D);
        float4 v0 = p[0], v1 = p[1];
        float s = sum8(v0, v1);
        s += __shfl_xor(s, 1, 64);
        s += __shfl_xor(s, 2, 64);
        s += __shfl_xor(s, 4, 64);
        s += __shfl_xor(s, 8, 64);
        float gmv = s * inv_gs;
        if (leader) gmo[t - t0] = gmv;
        if (mb[t]) {                       // wave-uniform branch
            n += 1.f;
            float d = gmv - mean;
            mean += __fdividef(d, n);
            m2 = fmaf(d, gmv - mean, m2);
        }
    }
    if (leader) {
        const int S = NC * B * NGROUPS;
        const int idx = c * (B * NGROUPS) + b * NGROUPS + g;
        loc[idx] = n; loc[S + idx] = mean; loc[2 * S + idx] = m2;
    }
}

// ---------------- K2: chunk-prefix scan (LDS-resident) + final outputs ----------------
// 1 block, 256 threads. Preload all aggregates into LDS (coalesced), then 64 chains
// scan serially from LDS (lane l reads word c*64+l: 2-way bank alias = free).
__global__ void ts_scan(const int* __restrict__ prev_count,
                        const float* __restrict__ prev_mean,
                        const float* __restrict__ prev_var,
                        const float* __restrict__ loc,
                        float* __restrict__ pref,
                        float* __restrict__ out_count,
                        float* __restrict__ out_mean,
                        float* __restrict__ out_var,
                        int B, int NC)
{
    extern __shared__ float s_loc[];       // 3 * NC * BG floats
    const int BG = B * NGROUPS;
    const int S  = NC * BG;
    for (int i = threadIdx.x; i < 3 * S; i += blockDim.x) s_loc[i] = loc[i];
    __syncthreads();

    const int chain = threadIdx.x;
    if (chain >= BG) return;
    const int b = chain / NGROUPS;
    const int g = chain % NGROUPS;

    float n    = (float)prev_count[b];
    float mean = prev_mean[chain];
    float m2   = prev_var[chain] * fmaxf(n, 1.0f);

    for (int c = 0; c < NC; ++c) {
        const int idx = c * BG + chain;
        pref[idx] = n; pref[S + idx] = mean; pref[2 * S + idx] = m2;
        float nb = s_loc[idx];
        if (nb > 0.f) {
            float mb_ = s_loc[S + idx];
            float m2b = s_loc[2 * S + idx];
            float nn  = n + nb;
            float d   = mb_ - mean;
            float r   = nb / nn;
            mean += d * r;
            m2   += m2b + d * d * (n * r);
            n = nn;
        }
    }
    if (g == 0) out_count[b] = n;
    out_mean[chain] = mean;
    out_var[chain]  = fmaxf(__fdividef(m2, fmaxf(n, 1.f)), VFLOOR);
}

// ---------------- K3: per-timestep replay -> mean_t / rstd_t ----------------
// one thread per (chain, chunk): 32 serial scalar Welford steps from gm.
// mean/rstd layout: [b][c][g][j] (same as gm).
__global__ void __launch_bounds__(256)
ts_replay(const int* __restrict__ mask,
          const float* __restrict__ gm_buf, const float* __restrict__ pref,
          float* __restrict__ mean_buf, float* __restrict__ rstd_buf,
          int B, int L, int NC)
{
    const int BG  = B * NGROUPS;
    const int S   = NC * BG;
    const int tidg = blockIdx.x * blockDim.x + threadIdx.x;
    if (tidg >= S) return;
    const int c     = tidg / BG;
    const int chain = tidg % BG;
    const int b     = chain / NGROUPS;
    const int g     = chain % NGROUPS;

    const int idx = c * BG + chain;
    float n    = pref[idx];
    float mean = pref[S + idx];
    float m2   = pref[2 * S + idx];

    const size_t base = (((size_t)b * NC + c) * NGROUPS + g) * CHUNK;
    const int* mrow = mask + (size_t)b * L + c * CHUNK;
    const int jmax = min(CHUNK, L - c * CHUNK);

    #pragma unroll 8
    for (int j = 0; j < jmax; ++j) {
        float gmv = gm_buf[base + j];
        if (mrow[j]) {
            n += 1.f;
            float d = gmv - mean;
            mean += __fdividef(d, n);
            m2 = fmaf(d, gmv - mean, m2);
        }
        float var = fmaxf(__fdividef(m2, fmaxf(n, 1.f)), VFLOOR);
        mean_buf[base + j] = mean;
        rstd_buf[base + j] = rsqrtf(var + EPS_F);
    }
}

// ---------------- K4: pure streaming normalize ----------------
// grid-stride; thread handles 8 consecutive d. d8 is invariant across grid-stride
// iterations (stride % VPR == 0), so affine params are hoisted out of the loop.
__global__ void __launch_bounds__(256)
ts_norm(const float* __restrict__ x,
        const float* __restrict__ weight, const float* __restrict__ bias,
        const float* __restrict__ mean_buf, const float* __restrict__ rstd_buf,
        float* __restrict__ y,
        int B, int L, int D, int NC)
{
    const int VPR = D / 8;                       // vec8 per row (=256)
    const size_t total = (size_t)B * L * VPR;
    const size_t stride = (size_t)gridDim.x * blockDim.x;
    size_t i = (size_t)blockIdx.x * blockDim.x + threadIdx.x;
    if (i >= total) return;

    const int d8 = (int)(i % VPR);
    const int g  = d8 / (VPR / NGROUPS);

    const float4* wp = (const float4*)(weight + d8 * 8);
    const float4* hp = (const float4*)(bias + d8 * 8);
    float4 w0 = wp[0], w1 = wp[1];
    float4 h0 = hp[0], h1 = hp[1];
    w0.x += 1.f; w0.y += 1.f; w0.z += 1.f; w0.w += 1.f;
    w1.x += 1.f; w1.y += 1.f; w1.z += 1.f; w1.w += 1.f;

    for (; i < total; i += stride) {
        const size_t row = i / VPR;              // = b*L + t
        const int b = (int)(row / L);
        const int t = (int)(row % L);
        const int c = t / CHUNK, j = t % CHUNK;
        const size_t sidx = (((size_t)b * NC + c) * NGROUPS + g) * CHUNK + j;
        float mean = mean_buf[sidx];
        float rstd = rstd_buf[sidx];

        const float4* p = (const float4*)(x + i * 8);
        float4 v0 = p[0], v1 = p[1];
        float4 o0, o1;
        o0.x = fmaf((v0.x - mean) * rstd, w0.x, h0.x);
        o0.y = fmaf((v0.y - mean) * rstd, w0.y, h0.y);
        o0.z = fmaf((v0.z - mean) * rstd, w0.z, h0.z);
        o0.w = fmaf((v0.w - mean) * rstd, w0.w, h0.w);
        o1.x = fmaf((v1.x - mean) * rstd, w1.x, h1.x);
        o1.y = fmaf((v1.y - mean) * rstd, w1.y, h1.y);
        o1.z = fmaf((v1.z - mean) * rstd, w1.z, h1.z);
        o1.w = fmaf((v1.w - mean) * rstd, w1.w, h1.w);
        float4* q = (float4*)(y + i * 8);
        q[0] = o0; q[1] = o1;
    }
}

extern "C" void kernel_launch(void* const* d_in, const int* in_sizes, int n_in,
                              void* d_out, int out_size, void* d_ws, size_t ws_size,
                              hipStream_t stream) {
    const float* x          = (const float*)d_in[0];
    const int*   prev_count = (const int*)d_in[1];
    const float* prev_mean  = (const float*)d_in[2];
    const float* prev_var   = (const float*)d_in[3];
    const int*   mask       = (const int*)d_in[4];     // bool stored as int32
    const float* weight     = (const float*)d_in[5];
    const float* bias       = (const float*)d_in[6];

    const int B  = in_sizes[1];
    const int D  = in_sizes[5];
    const int L  = in_sizes[4] / B;
    const int NC = (L + CHUNK - 1) / CHUNK;
    const int BG = B * NGROUPS;
    const int S  = NC * BG;
    const float inv_gs = (float)NGROUPS / (float)D;

    float* out = (float*)d_out;
    const size_t yN = (size_t)B * L * D;
    float* out_y     = out;
    float* out_count = out + yN;
    float* out_mean  = out + yN + B;
    float* out_var   = out + yN + B + BG;

    float* ws = (float*)d_ws;
    const size_t gmN = (size_t)B * NC * NGROUPS * CHUNK;   // >= B*L*G
    float* gm_buf   = ws;
    float* mean_buf = gm_buf + gmN;
    float* rstd_buf = mean_buf + gmN;
    float* loc      = rstd_buf + gmN;        // 3*S
    float* pref     = loc + 3 * (size_t)S;   // 3*S

    dim3 blk(D / 8);   // 256

    ts_gm_agg<<<B * NC, blk, 0, stream>>>(x, mask, gm_buf, loc, B, L, D, NC, inv_gs);

    const size_t smem = 3 * (size_t)S * sizeof(float);    // 96 KiB
    ts_scan<<<1, 256, smem, stream>>>(prev_count, prev_mean, prev_var, loc, pref,
                                      out_count, out_mean, out_var, B, NC);

    ts_replay<<<(S + 255) / 256, 256, 0, stream>>>(mask, gm_buf, pref,
                                                   mean_buf, rstd_buf, B, L, NC);

    ts_norm<<<1024, 256, 0, stream>>>(x, weight, bias, mean_buf, rstd_buf,
                                      out_y, B, L, D, NC);
}

// Round 4
// 273.591 us; speedup vs baseline: 1.2118x; 1.1785x over previous
//
#include <hip/hip_runtime.h>

#define NGROUPS 16          // G
#define TPG     16          // threads (lanes) per group in the reduce = 16
#define CHUNK   32          // timesteps per chunk
#define EPS_F   1e-5f
#define VFLOOR  1e-6f

__device__ __forceinline__ float sum8(const float4& a, const float4& b) {
    return ((a.x + a.y) + (a.z + a.w)) + ((b.x + b.y) + (b.z + b.w));
}

// Chan/Welford set-union merge: (na,ma,m2a) ∪= (nb,mb,m2b). Commutative.
// Guard nb>0 keeps identity (0,0,0) and empty-chunk merges exact.
__device__ __forceinline__ void wmerge(float& na, float& ma, float& m2a,
                                       float nb, float mb, float m2b) {
    if (nb > 0.f) {
        float nn = na + nb;
        float d  = mb - ma;
        float r  = nb / nn;
        ma  = fmaf(d, r, ma);
        m2a = m2a + m2b + d * d * (na * r);
        na  = nn;
    }
}

// ---------------- K1: group means + per-chunk Welford aggregates ----------------
// grid = B*NC, block = D/8 = 256. The only HBM read of x.
// gm layout:   [b][c][g][j]          (contiguous per (chain,chunk) for K2 replay)
// loc4 layout: [b][g][c] float4{n,mean,m2,_}  (contiguous in c for K2 pred-reduce)
__global__ void __launch_bounds__(256)
ts_gm_agg(const float* __restrict__ x, const int* __restrict__ mask,
          float* __restrict__ gm_buf, float4* __restrict__ loc4,
          int B, int L, int D, int NC, float inv_gs)
{
    const int b   = blockIdx.x / NC;
    const int c   = blockIdx.x % NC;
    const int tid = threadIdx.x;
    const int g   = tid / TPG;
    const bool leader = (tid & (TPG - 1)) == 0;
    const int t0  = c * CHUNK;
    const int t1  = min(t0 + CHUNK, L);

    const float* xb = x + (size_t)b * L * D + tid * 8;
    const int*   mb = mask + (size_t)b * L;
    float* gmo = gm_buf + (((size_t)b * NC + c) * NGROUPS + g) * CHUNK;

    float n = 0.f, mean = 0.f, m2 = 0.f;
    #pragma unroll 4
    for (int t = t0; t < t1; ++t) {
        const float4* p = (const float4*)(xb + (size_t)t * D);
        float4 v0 = p[0], v1 = p[1];
        float s = sum8(v0, v1);
        s += __shfl_xor(s, 1, 64);
        s += __shfl_xor(s, 2, 64);
        s += __shfl_xor(s, 4, 64);
        s += __shfl_xor(s, 8, 64);
        float gmv = s * inv_gs;
        if (leader) gmo[t - t0] = gmv;
        if (mb[t]) {                       // wave-uniform branch
            n += 1.f;
            float d = gmv - mean;
            mean += __fdividef(d, n);
            m2 = fmaf(d, gmv - mean, m2);
        }
    }
    if (leader) {
        loc4[((size_t)b * NGROUPS + g) * NC + c] = make_float4(n, mean, m2, 0.f);
    }
}

// ---------------- K2: fused pred-reduce + replay + normalize ----------------
// grid = B*NC, block = 256. Block (b,c):
//  1. lanes (g,k) merge predecessor aggregates c'=k,k+16,... (L2 hits)
//  2. 4-step shfl tree -> chunk-union per group; merge with prev-chain state
//  3. leaders replay 32 sequential Welford steps from gm -> s_mean/s_rstd (LDS)
//  4. all threads normalize the chunk (x re-read = L3 hit) and write y
__global__ void __launch_bounds__(256)
ts_fused(const float* __restrict__ x, const int* __restrict__ mask,
         const float* __restrict__ gm_buf, const float4* __restrict__ loc4,
         const int* __restrict__ prev_count, const float* __restrict__ prev_mean,
         const float* __restrict__ prev_var,
         const float* __restrict__ weight, const float* __restrict__ bias,
         float* __restrict__ y, float* __restrict__ out_count,
         float* __restrict__ out_mean, float* __restrict__ out_var,
         int B, int L, int D, int NC)
{
    __shared__ float s_mean[NGROUPS][CHUNK + 1];   // +1 pad: leader writes stride 33
    __shared__ float s_rstd[NGROUPS][CHUNK + 1];

    const int b   = blockIdx.x / NC;
    const int c   = blockIdx.x % NC;
    const int tid = threadIdx.x;
    const int g   = tid / TPG;
    const int k   = tid & (TPG - 1);
    const int chain = b * NGROUPS + g;

    // --- 1. parallel predecessor reduce (commutative set-union) ---
    float n = 0.f, mean = 0.f, m2 = 0.f;
    const float4* lrow = loc4 + (size_t)chain * NC;
    for (int cp = k; cp < c; cp += TPG) {
        float4 v = lrow[cp];
        wmerge(n, mean, m2, v.x, v.y, v.z);
    }
    // --- 2. shfl tree over the 16 lanes of this group ---
    #pragma unroll
    for (int o = 1; o < TPG; o <<= 1) {
        float on = __shfl_xor(n, o, 64);
        float om = __shfl_xor(mean, o, 64);
        float o2 = __shfl_xor(m2, o, 64);
        wmerge(n, mean, m2, on, om, o2);
    }
    // merge prev-chain state (prev ∪ chunk-union; commutative)
    {
        float pn = (float)prev_count[b];
        float pm = prev_mean[chain];
        float p2 = prev_var[chain] * fmaxf(pn, 1.0f);
        wmerge(pn, pm, p2, n, mean, m2);
        n = pn; mean = pm; m2 = p2;
    }

    // --- 3. leaders replay the chunk's per-timestep states into LDS ---
    const int t0 = c * CHUNK;
    const int jmax = min(CHUNK, L - t0);
    if (k == 0) {
        const float* gmo = gm_buf + (((size_t)b * NC + c) * NGROUPS + g) * CHUNK;
        const int*   mrow = mask + (size_t)b * L + t0;
        float var = fmaxf(__fdividef(m2, fmaxf(n, 1.f)), VFLOOR);
        #pragma unroll 8
        for (int j = 0; j < jmax; ++j) {
            float gmv = gmo[j];
            if (mrow[j]) {
                n += 1.f;
                float d = gmv - mean;
                mean += __fdividef(d, n);
                m2 = fmaf(d, gmv - mean, m2);
            }
            var = fmaxf(__fdividef(m2, fmaxf(n, 1.f)), VFLOOR);
            s_mean[g][j] = mean;
            s_rstd[g][j] = rsqrtf(var + EPS_F);
        }
        if (c == NC - 1) {
            out_mean[chain] = mean;
            out_var[chain]  = var;
            if (g == 0) out_count[b] = n;
        }
    }

    // --- 4. normalize the chunk ---
    const float4* wp = (const float4*)(weight + tid * 8);
    const float4* hp = (const float4*)(bias + tid * 8);
    float4 w0 = wp[0], w1 = wp[1];
    float4 h0 = hp[0], h1 = hp[1];
    w0.x += 1.f; w0.y += 1.f; w0.z += 1.f; w0.w += 1.f;
    w1.x += 1.f; w1.y += 1.f; w1.z += 1.f; w1.w += 1.f;

    __syncthreads();

    const float* xb = x + ((size_t)b * L + t0) * D + tid * 8;
    float*       yb = y + ((size_t)b * L + t0) * D + tid * 8;
    #pragma unroll 2
    for (int j = 0; j < jmax; ++j) {
        float m_ = s_mean[g][j];           // broadcast within 16-lane cohort
        float r_ = s_rstd[g][j];
        const float4* p = (const float4*)(xb + (size_t)j * D);
        float4 v0 = p[0], v1 = p[1];
        float4 o0, o1;
        o0.x = fmaf((v0.x - m_) * r_, w0.x, h0.x);
        o0.y = fmaf((v0.y - m_) * r_, w0.y, h0.y);
        o0.z = fmaf((v0.z - m_) * r_, w0.z, h0.z);
        o0.w = fmaf((v0.w - m_) * r_, w0.w, h0.w);
        o1.x = fmaf((v1.x - m_) * r_, w1.x, h1.x);
        o1.y = fmaf((v1.y - m_) * r_, w1.y, h1.y);
        o1.z = fmaf((v1.z - m_) * r_, w1.z, h1.z);
        o1.w = fmaf((v1.w - m_) * r_, w1.w, h1.w);
        float4* q = (float4*)(yb + (size_t)j * D);
        q[0] = o0; q[1] = o1;
    }
}

extern "C" void kernel_launch(void* const* d_in, const int* in_sizes, int n_in,
                              void* d_out, int out_size, void* d_ws, size_t ws_size,
                              hipStream_t stream) {
    const float* x          = (const float*)d_in[0];
    const int*   prev_count = (const int*)d_in[1];
    const float* prev_mean  = (const float*)d_in[2];
    const float* prev_var   = (const float*)d_in[3];
    const int*   mask       = (const int*)d_in[4];     // bool stored as int32
    const float* weight     = (const float*)d_in[5];
    const float* bias       = (const float*)d_in[6];

    const int B  = in_sizes[1];
    const int D  = in_sizes[5];
    const int L  = in_sizes[4] / B;
    const int NC = (L + CHUNK - 1) / CHUNK;
    const int BG = B * NGROUPS;
    const float inv_gs = (float)NGROUPS / (float)D;

    float* out = (float*)d_out;
    const size_t yN = (size_t)B * L * D;
    float* out_y     = out;
    float* out_count = out + yN;
    float* out_mean  = out + yN + B;
    float* out_var   = out + yN + B + BG;

    // workspace: gm_buf (B*NC*G*CHUNK floats = 1 MB), loc4 (B*G*NC float4 = 128 KB)
    float* ws = (float*)d_ws;
    const size_t gmN = (size_t)B * NC * NGROUPS * CHUNK;
    float*  gm_buf = ws;
    float4* loc4   = (float4*)(ws + gmN);

    dim3 blk(D / 8);   // 256

    ts_gm_agg<<<B * NC, blk, 0, stream>>>(x, mask, gm_buf, loc4, B, L, D, NC, inv_gs);

    ts_fused<<<B * NC, blk, 0, stream>>>(x, mask, gm_buf, loc4,
                                         prev_count, prev_mean, prev_var,
                                         weight, bias,
                                         out_y, out_count, out_mean, out_var,
                                         B, L, D, NC);
}